// Round 5
// baseline (485.533 us; speedup 1.0000x reference)
//
#include <hip/hip_runtime.h>
#include <math.h>

// B=2,H=16,L=2048,D=128. out = int32(softmax(qk^T * sqrt(128)) v); mask all-false.
// Reference = numpy fp32 port with OpenBLAS sgemm semantics (verified PASS):
//   qk:  per element, sequential fp32 FMA chain over d=0..127, then * scale
//   softmax: max, exp (correctly rounded via fp64), pairwise sum (AVX512 model), IEEE div
//   PV:  FMA chains per 384-wide k-chunk, chunks added in ascending order
// Round 5:
//   * screen: 2-tile ping-pong register pipeline (loads for t+2 issue after MFMAs
//     consume tile t -> ~1.5-body latency window, vmcnt(4) steady state);
//     reduce = 2 shuffle levels + 4-carrier fire-and-forget atomicMax (rmaxI content
//     bit-identical, same cadence -> same thresholds -> same candidate set);
//     s_setprio dropped (negative on lockstep GEMM loops).
//   * finish: 512 threads (16 thr/row phases, numerator 8 rounds of 4 rows);
//     numerator V-batches double-buffered across rounds (issue p+1, compute p).

#define KL 2048
#define KD 128
#define TQ 32
#define CAPS 96             /* superset capacity (collection) */
#define CAPF 40             /* final capacity (post-prune, matches verified kernel) */
#define QP 132              /* Qs LDS row stride (floats) */
#define GEMMQ 384           /* OpenBLAS SGEMM_DEFAULT_Q */
#define SCALEF 0x1.6A09E6p+3f   /* fp32(sqrt(fp32(128))) */
#define CUTU 4.35f          /* unscaled approx cut: 4.35*11.31 = 49.2 scaled */

#define KH_ELEMS  (2 * 16 * KL * KD)           /* 8388608 bf16 */
#define NROWS     (2 * 16 * KL)                /* 65536 rows */

typedef __attribute__((ext_vector_type(8))) short bf16x8;
typedef __attribute__((ext_vector_type(4))) float f32x4;

static __device__ __forceinline__ unsigned short f2bf(float f) {
    unsigned u = __float_as_uint(f);
    return (unsigned short)((u + 0x7FFFu + ((u >> 16) & 1u)) >> 16);  // RNE
}

// monotone float<->unsigned key for LDS atomicMax on floats
static __device__ __forceinline__ unsigned fkey(float f) {
    const unsigned u = __float_as_uint(f);
    return u ^ ((unsigned)((int)u >> 31) | 0x80000000u);
}
static __device__ __forceinline__ float funkey(unsigned k) {
    return __uint_as_float(k ^ ((unsigned)(~((int)k >> 31)) | 0x80000000u));
}

__global__ void __launch_bounds__(256)
cvt_k_bf16(const float* __restrict__ kp, unsigned short* __restrict__ kh) {
    const int i4 = (blockIdx.x * 256 + threadIdx.x) * 4;   // 8388608 floats total
    const float4 v = *(const float4*)(kp + i4);
    ushort4 h; h.x = f2bf(v.x); h.y = f2bf(v.y); h.z = f2bf(v.z); h.w = f2bf(v.w);
    *(ushort4*)(kh + i4) = h;
}

// ======================= kernel 1: MFMA screening =======================
__global__ void __launch_bounds__(256)
attn_screen(const float* __restrict__ qp, const unsigned short* __restrict__ kh,
            int* __restrict__ gcnt, unsigned short* __restrict__ gcand)
{
    __shared__ unsigned       rmaxI[TQ];        // shared online max (fkey-mapped)
    __shared__ int            cnt[TQ];
    __shared__ unsigned short candK[TQ * CAPS];
    __shared__ float          candS[TQ * CAPS];

    const int tid  = threadIdx.x;
    const int lane = tid & 63;
    const int wave = tid >> 6;
    const int l15  = lane & 15;
    const int quad = lane >> 4;

    // XCD-aware swizzle: each XCD owns 4 consecutive bh (kh slab 2MB, L2-resident)
    const int lin = blockIdx.y * (KL / TQ) + blockIdx.x;   // 0..2047
    const int nl  = (lin & 7) * 256 + (lin >> 3);          // bijective (2048 = 8*256)
    const int bh  = nl >> 6;
    const int q0  = (nl & 63) * TQ;

    const size_t base  = (size_t)bh * (KL * KD);
    const size_t baseh = (size_t)bh * KL * KD;

    if (tid < TQ) { cnt[tid] = 0; rmaxI[tid] = 0x00800000u; /* fkey(-3.4e38) */ }

    // ---- build A-fragments (Q in bf16): a=0 rows 0-15, a=1 rows 16-31 ----
    bf16x8 aA[2][4];
    #pragma unroll
    for (int a = 0; a < 2; ++a)
        #pragma unroll
        for (int s = 0; s < 4; ++s) {
            const int row = q0 + a * 16 + l15;
            const int d0 = s * 32 + quad * 8;
            const float4 x = *(const float4*)(qp + base + (size_t)row * KD + d0);
            const float4 y = *(const float4*)(qp + base + (size_t)row * KD + d0 + 4);
            bf16x8 af;
            af[0] = (short)f2bf(x.x); af[1] = (short)f2bf(x.y);
            af[2] = (short)f2bf(x.z); af[3] = (short)f2bf(x.w);
            af[4] = (short)f2bf(y.x); af[5] = (short)f2bf(y.y);
            af[6] = (short)f2bf(y.z); af[7] = (short)f2bf(y.w);
            aA[a][s] = af;
        }
    __syncthreads();    // cnt/rmaxI init visible before any atomics

    float rmaxL[8];     // per-lane running max (4-group folded at reduce points)
    float thrR[8];      // cached per-row collection threshold (lags; superset-safe)
    #pragma unroll
    for (int i = 0; i < 8; ++i) rmaxL[i] = -3.4e38f;

    const unsigned short* kwbase =
        kh + baseh + (size_t)(16 * wave + l15) * KD + quad * 8;

#define LOADT(D0, D1, D2, D3, TT) { \
    const unsigned short* kb_ = kwbase + (size_t)(TT) * 64 * KD; \
    D0 = *(const bf16x8*)(kb_ + 0); \
    D1 = *(const bf16x8*)(kb_ + 32); \
    D2 = *(const bf16x8*)(kb_ + 64); \
    D3 = *(const bf16x8*)(kb_ + 96); }

#define MFMA8(S0, S1, S2, S3) { \
    ac0 = (f32x4){0.f,0.f,0.f,0.f}; ac1 = (f32x4){0.f,0.f,0.f,0.f}; \
    ac0 = __builtin_amdgcn_mfma_f32_16x16x32_bf16(aA[0][0], S0, ac0, 0,0,0); \
    ac1 = __builtin_amdgcn_mfma_f32_16x16x32_bf16(aA[1][0], S0, ac1, 0,0,0); \
    ac0 = __builtin_amdgcn_mfma_f32_16x16x32_bf16(aA[0][1], S1, ac0, 0,0,0); \
    ac1 = __builtin_amdgcn_mfma_f32_16x16x32_bf16(aA[1][1], S1, ac1, 0,0,0); \
    ac0 = __builtin_amdgcn_mfma_f32_16x16x32_bf16(aA[0][2], S2, ac0, 0,0,0); \
    ac1 = __builtin_amdgcn_mfma_f32_16x16x32_bf16(aA[1][2], S2, ac1, 0,0,0); \
    ac0 = __builtin_amdgcn_mfma_f32_16x16x32_bf16(aA[0][3], S3, ac0, 0,0,0); \
    ac1 = __builtin_amdgcn_mfma_f32_16x16x32_bf16(aA[1][3], S3, ac1, 0,0,0); }

// 2-level fold (xor 1,2) + 4-carrier atomicMax: carriers (l15&3)==0 cover the
// four disjoint 4-lane groups -> rmaxI receives max over ALL 16 lanes, exactly
// as the old 4-level butterfly + single-carrier version did.
#define RMAX_SHARE() { \
    _Pragma("unroll") \
    for (int a2 = 0; a2 < 2; ++a2) { \
        _Pragma("unroll") \
        for (int g2 = 0; g2 < 4; ++g2) { \
            float vv = rmaxL[a2 * 4 + g2]; \
            vv = fmaxf(vv, __shfl_xor(vv, 1, 64)); \
            vv = fmaxf(vv, __shfl_xor(vv, 2, 64)); \
            rmaxL[a2 * 4 + g2] = vv; \
            if ((l15 & 3) == 0) \
                atomicMax(&rmaxI[a2 * 16 + quad * 4 + g2], fkey(vv)); \
        } } }

#define THR_REFRESH() { \
    _Pragma("unroll") \
    for (int a2 = 0; a2 < 2; ++a2) { \
        _Pragma("unroll") \
        for (int g2 = 0; g2 < 4; ++g2) \
            thrR[a2 * 4 + g2] = funkey(__hip_atomic_load( \
                    &rmaxI[a2 * 16 + quad * 4 + g2], \
                    __ATOMIC_RELAXED, __HIP_MEMORY_SCOPE_WORKGROUP)) - CUTU; \
    } }

// per-lane collect: order nondeterministic, final SET deterministic
#define COLLECT(TT) { \
    _Pragma("unroll") \
    for (int a2 = 0; a2 < 2; ++a2) { \
        _Pragma("unroll") \
        for (int g2 = 0; g2 < 4; ++g2) { \
            const int j2 = a2 * 4 + g2; \
            const float sc = (a2 == 0) ? ac0[g2] : ac1[g2]; \
            rmaxL[j2] = fmaxf(rmaxL[j2], sc); \
            if (sc > thrR[j2]) { \
                const int row = a2 * 16 + quad * 4 + g2; \
                const int idx = atomicAdd(&cnt[row], 1); \
                if (idx < CAPS) { \
                    candK[row * CAPS + idx] = \
                        (unsigned short)((TT) * 64 + 16 * wave + l15); \
                    candS[row * CAPS + idx] = sc; \
                } } } } }

    f32x4 ac0, ac1;

    // ---- pre-peek tiles 0,1: seed shared row maxima (no collection) ----
    {
        bf16x8 P0, P1, P2, P3;
        #pragma unroll 1
        for (int tp = 0; tp < 2; ++tp) {
            LOADT(P0, P1, P2, P3, tp);
            MFMA8(P0, P1, P2, P3);
            #pragma unroll
            for (int a = 0; a < 2; ++a)
                #pragma unroll
                for (int g = 0; g < 4; ++g)
                    rmaxL[a * 4 + g] = fmaxf(rmaxL[a * 4 + g],
                                             (a == 0) ? ac0[g] : ac1[g]);
        }
        RMAX_SHARE();
    }
    __syncthreads();
    THR_REFRESH();

    // ============== main pass: 2-tile ping-pong register pipeline ==============
    bf16x8 A0, A1, A2, A3, B0, B1, B2, B3;
    LOADT(A0, A1, A2, A3, 0);
    LOADT(B0, B1, B2, B3, 1);

    #pragma unroll 1
    for (int i = 0; i < KL / 128; ++i) {        // 16 iterations, 2 tiles each
        const int tA = 2 * i, tB = 2 * i + 1;
        // ---- body A: compute tile tA, then prefetch tA+2 into A-slots ----
        MFMA8(A0, A1, A2, A3);
        { const int tn = (tA + 2 < KL / 64) ? tA + 2 : KL / 64 - 1;
          LOADT(A0, A1, A2, A3, tn); }
        COLLECT(tA);
        // ---- body B: compute tile tB, then prefetch tB+2 into B-slots ----
        MFMA8(B0, B1, B2, B3);
        { const int tn = (tB + 2 < KL / 64) ? tB + 2 : KL / 64 - 1;
          LOADT(B0, B1, B2, B3, tn); }
        COLLECT(tB);
        // every 4th tile (after tiles 3,7,...,31): share maxima + refresh thr
        if (i & 1) { RMAX_SHARE(); THR_REFRESH(); }
    }
    // tile 31 hit the reduce -> rmaxI now holds the exact row maxima
    __syncthreads();

    // ---- exact final max, prune superset, sort ascending, write to workspace ----
    if (tid < TQ) {
        const float rm = funkey(rmaxI[tid]);
        const float thr = rm - CUTU;            // same fp32 op as two-pass kernel
        const int n0 = min(cnt[tid], CAPS);
        unsigned short* ck = &candK[tid * CAPS];
        float* cs = &candS[tid * CAPS];
        int m = 0;
        for (int i = 0; i < n0; ++i)
            if (cs[i] > thr) ck[m++] = ck[i];   // exact final candidate set
        if (m > CAPF) m = CAPF;
        for (int i = 1; i < m; ++i) {
            const unsigned short key = ck[i];
            int j = i - 1;
            while (j >= 0 && ck[j] > key) { ck[j + 1] = ck[j]; --j; }
            ck[j + 1] = key;
        }
        const int grow = bh * KL + q0 + tid;
        gcnt[grow] = m;
        unsigned short* gc = gcand + (size_t)grow * CAPF;
        for (int i = 0; i < m; ++i) gc[i] = ck[i];
    }
}

// ======================= kernel 2: exact finisher (512 thr) =======================
__global__ void __launch_bounds__(512)
attn_finish(const float* __restrict__ qp, const float* __restrict__ kp,
            const float* __restrict__ vp, const float* __restrict__ queryp,
            const unsigned char* __restrict__ maskp,
            const int* __restrict__ gcnt, const unsigned short* __restrict__ gcand,
            int* __restrict__ outp)
{
#pragma clang fp contract(off)
    __shared__ float          Qs[TQ * QP];      // fp32 Q rows (reused as softmax pad)
    __shared__ int            cntA[TQ];
    __shared__ unsigned short candK[TQ * CAPF];
    __shared__ float          candS[TQ * CAPF];
    __shared__ float          candA[TQ * CAPF];
    __shared__ float          rowM[TQ];
    __shared__ float          rowSig[TQ];

    const int tid = threadIdx.x;    // 0..511

    const int lin = blockIdx.y * (KL / TQ) + blockIdx.x;   // 0..2047
    const int nl  = (lin & 7) * 256 + (lin >> 3);          // same swizzle as screen
    const int bh  = nl >> 6;
    const int q0  = (nl & 63) * TQ;

    const size_t base = (size_t)bh * (KL * KD);
    const int rowbase = bh * KL + q0;

    // ---- stage Q fp32 into LDS + pull candidates from workspace ----
    #pragma unroll
    for (int i = 0; i < 2; ++i) {
        const int idx = tid + i * 512, r = idx >> 5, c4 = (idx & 31) << 2;
        *(float4*)&Qs[r * QP + c4] =
            *(const float4*)(qp + base + (size_t)(q0 + r) * KD + c4);
    }
    {
        const unsigned short* gc = gcand + (size_t)rowbase * CAPF;
        #pragma unroll
        for (int i = 0; i < (TQ * CAPF + 511) / 512; ++i) {
            const int idx = tid + i * 512;
            if (idx < TQ * CAPF) candK[idx] = gc[idx];
        }
        if (tid < TQ) cntA[tid] = gcnt[rowbase + tid];
    }
    __syncthreads();

    // ================= exact fp32 dots for candidates (BLAS chain) =================
    {
        const int r = tid >> 4, j = tid & 15;
        const int n = cntA[r];
        const float* qrow = &Qs[r * QP];
        for (int i = j; i < n; i += 16) {
            const int kk = candK[r * CAPF + i];
            const float* krow = kp + base + (size_t)kk * KD;
            float s = 0.f;
            #pragma unroll 8
            for (int d = 0; d < KD; d += 4) {
                const float4 kv = *(const float4*)(krow + d);
                const float4 qv = *(const float4*)(qrow + d);
                s = fmaf(qv.x, kv.x, s);
                s = fmaf(qv.y, kv.y, s);
                s = fmaf(qv.z, kv.z, s);
                s = fmaf(qv.w, kv.w, s);
            }
            candS[r * CAPF + i] = s * SCALEF;
        }
    }
    __syncthreads();

    // ---- c1: per-row max (serial, n~4.5) ----
    if (tid < TQ) {
        const int n = cntA[tid];
        float m = -3.4e38f;
        for (int i = 0; i < n; ++i) m = fmaxf(m, candS[tid * CAPF + i]);
        rowM[tid] = m;
    }
    __syncthreads();

    // ---- c2: exp parallel 16 threads/row (same fp64 exp expression) ----
    {
        const int r = tid >> 4, j = tid & 15;
        const int n = cntA[r];
        const float m = rowM[r];
        for (int i = j; i < n; i += 16) {
            const float dm = candS[r * CAPF + i] - m;     // fp32 sub
            candA[r * CAPF + i] = (float)exp((double)dm); // ~correctly-rounded fp32 exp
        }
    }
    __syncthreads();

    // ---- c3: numpy pairwise denominator (AVX512 model), cb==2 fast path ----
    if (tid < TQ) {
        const int r = tid, n = cntA[r];
        float* E = &Qs[r * 129];    // reuse Q storage as 128-slot scatter pad
        float leaves[16];
        int p = 0;
        #pragma unroll 1
        for (int b = 0; b < 16; ++b) {
            const int pstart = p;
            while (p < n && (candK[r * CAPF + p] >> 7) == b) ++p;
            const int cb = p - pstart;
            float leaf = 0.0f;
            if (cb == 1) {
                leaf = candA[r * CAPF + pstart];
            } else if (cb == 2) {
                leaf = candA[r * CAPF + pstart] + candA[r * CAPF + pstart + 1];
            } else if (cb >= 3) {
                for (int jj = 0; jj < 128; ++jj) E[jj] = 0.0f;
                for (int jj = pstart; jj < p; ++jj)
                    E[candK[r * CAPF + jj] & 127] = candA[r * CAPF + jj];
                float R[16];
                for (int l = 0; l < 16; ++l)
                    R[l] = ((E[l] + E[16 + l]) + (E[32 + l] + E[48 + l]))
                         + ((E[64 + l] + E[80 + l]) + (E[96 + l] + E[112 + l]));
                for (int l = 0; l < 8; ++l) R[l] = R[l] + R[l + 8];
                for (int l = 0; l < 4; ++l) R[l] = R[l] + R[l + 4];
                R[0] = R[0] + R[2]; R[1] = R[1] + R[3];
                leaf = R[0] + R[1];
            }
            leaves[b] = leaf;
        }
        float t2[8], t3[4];
        for (int jj = 0; jj < 8; ++jj) t2[jj] = leaves[2 * jj] + leaves[2 * jj + 1];
        for (int jj = 0; jj < 4; ++jj) t3[jj] = t2[2 * jj] + t2[2 * jj + 1];
        rowSig[r] = (t3[0] + t3[1]) + (t3[2] + t3[3]);
    }
    __syncthreads();

    // ---- c4: division parallel 16 threads/row (IEEE fp32 div, same op) ----
    {
        const int r = tid >> 4, j = tid & 15;
        const int n = cntA[r];
        const float sig = rowSig[r];
        for (int i = j; i < n; i += 16)
            candA[r * CAPF + i] = candA[r * CAPF + i] / sig;
    }
    __syncthreads();

    // ====== numerator: FMA chain per 384-chunk, chunks added in order ======
    // 8 rounds of 4 rows (512 thr); batch-0 V loads double-buffered across
    // rounds (issue p+1 before computing p). Arithmetic chain bit-identical.
    {
        const int rq = tid >> 7;        // 0..3 (wave-uniform)
        const int d  = tid & 127;

        float paA[8], pvA[8]; int pcA[8];
        float paB[8], pvB[8]; int pcB[8];

#define NISSUE(RX, PA, PV, PC) { \
        const int nI = cntA[RX]; \
        _Pragma("unroll") \
        for (int u = 0; u < 8; ++u) { \
            const bool act = u < nI; \
            const int kk = act ? (int)candK[(RX) * CAPF + u] : 0; \
            PA[u] = act ? candA[(RX) * CAPF + u] : 0.0f; \
            PC[u] = (kk * 683) >> 18;              /* kk/384, exact kk<2048 */ \
            PV[u] = act ? vp[base + (size_t)kk * KD + d] : 0.0f; \
        } }

#define NCOMPUTE(RX, PA, PV, PC) { \
        const int nI = cntA[RX]; \
        float o = 0.0f, part = 0.0f; int cprev = 0; \
        _Pragma("unroll") \
        for (int u = 0; u < 8; ++u) { \
            if (u < nI) { \
                if (PC[u] != cprev) { o = o + part; part = 0.0f; cprev = PC[u]; } \
                part = fmaf(PA[u], PV[u], part); \
            } } \
        _Pragma("unroll 1") \
        for (int i0 = 8; i0 < nI; i0 += 8) { \
            float pa2[8], pv2[8]; int pc2[8]; \
            _Pragma("unroll") \
            for (int u = 0; u < 8; ++u) { \
                const int ix = i0 + u; \
                const bool act = ix < nI; \
                const int kk = act ? (int)candK[(RX) * CAPF + ix] : 0; \
                pa2[u] = act ? candA[(RX) * CAPF + ix] : 0.0f; \
                pc2[u] = (kk * 683) >> 18; \
                pv2[u] = act ? vp[base + (size_t)kk * KD + d] : 0.0f; \
            } \
            _Pragma("unroll") \
            for (int u = 0; u < 8; ++u) { \
                if (i0 + u < nI) { \
                    if (pc2[u] != cprev) { o = o + part; part = 0.0f; cprev = pc2[u]; } \
                    part = fmaf(pa2[u], pv2[u], part); \
                } } } \
        o = o + part; \
        int res = (int)o; \
        const int grow = q0 + (RX); \
        if (maskp[(size_t)bh * KL + grow]) \
            res = (int)queryp[base + (size_t)grow * KD + d]; \
        outp[base + (size_t)grow * KD + d] = res; }

        NISSUE(rq, paA, pvA, pcA);              // round 0 rows
        #pragma unroll 1
        for (int p = 0; p < 4; ++p) {
            const int rA = 8 * p + rq;
            const int rB = 8 * p + 4 + rq;
            NISSUE(rB, paB, pvB, pcB);
            NCOMPUTE(rA, paA, pvA, pcA);
            if (p < 3) { const int rN = 8 * (p + 1) + rq; NISSUE(rN, paA, pvA, pcA); }
            NCOMPUTE(rB, paB, pvB, pcB);
        }
    }
}

extern "C" void kernel_launch(void* const* d_in, const int* in_sizes, int n_in,
                              void* d_out, int out_size, void* d_ws, size_t ws_size,
                              hipStream_t stream) {
    const float* q     = (const float*)d_in[0];
    const float* k     = (const float*)d_in[1];
    const float* v     = (const float*)d_in[2];
    const float* query = (const float*)d_in[3];
    const unsigned char* mask = (const unsigned char*)d_in[4];
    // d_in[5] = dropout_p (static 0) -> identity, ignored.
    int* out = (int*)d_out;

    // workspace layout: kh (16.8MB) | gcnt (0.26MB) | gcand (5.24MB)
    unsigned short* kh    = (unsigned short*)d_ws;
    int*            gcnt  = (int*)((char*)d_ws + (size_t)KH_ELEMS * 2);
    unsigned short* gcand = (unsigned short*)((char*)d_ws + (size_t)KH_ELEMS * 2
                                              + (size_t)NROWS * 4);

    // pre-pass: K fp32 -> bf16 (8388608 floats, 4 per thread)
    cvt_k_bf16<<<dim3(8192), dim3(256), 0, stream>>>(k, kh);

    dim3 grid(KL / TQ, 32, 1);
    attn_screen<<<grid, dim3(256), 0, stream>>>(q, kh, gcnt, gcand);
    attn_finish<<<grid, dim3(512), 0, stream>>>(q, k, v, query, mask, gcnt, gcand, out);
}

// Round 6
// 361.942 us; speedup vs baseline: 1.3415x; 1.3415x over previous
//
#include <hip/hip_runtime.h>
#include <math.h>

// B=2,H=16,L=2048,D=128. out = int32(softmax(qk^T * sqrt(128)) v); mask all-false.
// Reference = numpy fp32 port with OpenBLAS sgemm semantics (verified PASS):
//   qk:  per element, sequential fp32 FMA chain over d=0..127, then * scale
//   softmax: max, exp (correctly rounded via fp64), pairwise sum (AVX512 model), IEEE div
//   PV:  FMA chains per 384-wide k-chunk, chunks added in ascending order
// Round 6:
//   * kh stored in MFMA-FRAGMENT ORDER [bh][g][s][quad][l15][8] by the cvt kernel:
//     screen's B-fragment loads become base + lane*16B -> one coalesced 1KB
//     transaction per load (was 16 scattered 64B granules per load, the round-3..5
//     invariant ~166us stall). Fragment contents byte-identical -> same scores.
//   * finish reverted to round-4 256-thread version (512-thr round-5 regressed +73us).

#define KL 2048
#define KD 128
#define TQ 32
#define CAPS 96             /* superset capacity (collection) */
#define CAPF 40             /* final capacity (post-prune, matches verified kernel) */
#define QP 132              /* Qs LDS row stride (floats) */
#define GEMMQ 384           /* OpenBLAS SGEMM_DEFAULT_Q */
#define SCALEF 0x1.6A09E6p+3f   /* fp32(sqrt(fp32(128))) */
#define CUTU 4.35f          /* unscaled approx cut: 4.35*11.31 = 49.2 scaled */

#define KH_ELEMS  (2 * 16 * KL * KD)           /* 8388608 bf16 */
#define NROWS     (2 * 16 * KL)                /* 65536 rows */

typedef __attribute__((ext_vector_type(8))) short bf16x8;
typedef __attribute__((ext_vector_type(4))) float f32x4;

static __device__ __forceinline__ unsigned short f2bf(float f) {
    unsigned u = __float_as_uint(f);
    return (unsigned short)((u + 0x7FFFu + ((u >> 16) & 1u)) >> 16);  // RNE
}

// monotone float<->unsigned key for LDS atomicMax on floats
static __device__ __forceinline__ unsigned fkey(float f) {
    const unsigned u = __float_as_uint(f);
    return u ^ ((unsigned)((int)u >> 31) | 0x80000000u);
}
static __device__ __forceinline__ float funkey(unsigned k) {
    return __uint_as_float(k ^ ((unsigned)(~((int)k >> 31)) | 0x80000000u));
}

// K fp32 -> bf16, scattered-read / coalesced-write, output in fragment order:
// ushort offset = bh*262144 + (g*16 + s*4 + quad)*128 + l15*8 + e
// holding K[bh][g*16+l15][s*32+quad*8+e], e=0..7.
__global__ void __launch_bounds__(256)
cvt_k_frag(const float* __restrict__ kp, unsigned short* __restrict__ kh) {
    const int c = blockIdx.x * 256 + threadIdx.x;   // 16B chunk id, 1048576 total
    const int bh = c >> 15;
    const int r  = c & 32767;
    const int l15 = r & 15, quad = (r >> 4) & 3, s = (r >> 6) & 3, g = r >> 8;
    const float* src = kp + ((size_t)bh << 18)
                     + (size_t)((g * 16 + l15) << 7) + s * 32 + quad * 8;
    const float4 x = *(const float4*)(src);
    const float4 y = *(const float4*)(src + 4);
    ushort4 h0, h1;
    h0.x = f2bf(x.x); h0.y = f2bf(x.y); h0.z = f2bf(x.z); h0.w = f2bf(x.w);
    h1.x = f2bf(y.x); h1.y = f2bf(y.y); h1.z = f2bf(y.z); h1.w = f2bf(y.w);
    unsigned short* dst = kh + (size_t)c * 8;
    *(ushort4*)(dst)     = h0;
    *(ushort4*)(dst + 4) = h1;
}

// ======================= kernel 1: MFMA screening =======================
__global__ void __launch_bounds__(256)
attn_screen(const float* __restrict__ qp, const unsigned short* __restrict__ kh,
            int* __restrict__ gcnt, unsigned short* __restrict__ gcand)
{
    __shared__ unsigned       rmaxI[TQ];        // shared online max (fkey-mapped)
    __shared__ int            cnt[TQ];
    __shared__ unsigned short candK[TQ * CAPS];
    __shared__ float          candS[TQ * CAPS];

    const int tid  = threadIdx.x;
    const int lane = tid & 63;
    const int wave = tid >> 6;
    const int l15  = lane & 15;
    const int quad = lane >> 4;

    // XCD-aware swizzle: each XCD owns 4 consecutive bh (kh slab 2MB, L2-resident)
    const int lin = blockIdx.y * (KL / TQ) + blockIdx.x;   // 0..2047
    const int nl  = (lin & 7) * 256 + (lin >> 3);          // bijective (2048 = 8*256)
    const int bh  = nl >> 6;
    const int q0  = (nl & 63) * TQ;

    const size_t base  = (size_t)bh * (KL * KD);
    const size_t baseh = (size_t)bh * KL * KD;

    if (tid < TQ) { cnt[tid] = 0; rmaxI[tid] = 0x00800000u; /* fkey(-3.4e38) */ }

    // ---- build A-fragments (Q in bf16): a=0 rows 0-15, a=1 rows 16-31 ----
    bf16x8 aA[2][4];
    #pragma unroll
    for (int a = 0; a < 2; ++a)
        #pragma unroll
        for (int s = 0; s < 4; ++s) {
            const int row = q0 + a * 16 + l15;
            const int d0 = s * 32 + quad * 8;
            const float4 x = *(const float4*)(qp + base + (size_t)row * KD + d0);
            const float4 y = *(const float4*)(qp + base + (size_t)row * KD + d0 + 4);
            bf16x8 af;
            af[0] = (short)f2bf(x.x); af[1] = (short)f2bf(x.y);
            af[2] = (short)f2bf(x.z); af[3] = (short)f2bf(x.w);
            af[4] = (short)f2bf(y.x); af[5] = (short)f2bf(y.y);
            af[6] = (short)f2bf(y.z); af[7] = (short)f2bf(y.w);
            aA[a][s] = af;
        }
    __syncthreads();    // cnt/rmaxI init visible before any atomics

    float rmaxL[8];     // per-lane running max (folded at reduce points)
    float thrR[8];      // cached per-row collection threshold (lags; superset-safe)
    #pragma unroll
    for (int i = 0; i < 8; ++i) rmaxL[i] = -3.4e38f;

    // fragment-order kh: wave's load for (g,s) = base(g,s) + lane*16B, coalesced.
    const unsigned short* kwbase = kh + baseh + (quad << 7) + (l15 << 3);

#define LOADT(D0, D1, D2, D3, TT) { \
    const unsigned short* kb_ = kwbase + ((size_t)((TT) * 4 + wave) << 11); \
    D0 = *(const bf16x8*)(kb_ + 0);    \
    D1 = *(const bf16x8*)(kb_ + 512);  \
    D2 = *(const bf16x8*)(kb_ + 1024); \
    D3 = *(const bf16x8*)(kb_ + 1536); }

#define MFMA8(S0, S1, S2, S3) { \
    ac0 = (f32x4){0.f,0.f,0.f,0.f}; ac1 = (f32x4){0.f,0.f,0.f,0.f}; \
    ac0 = __builtin_amdgcn_mfma_f32_16x16x32_bf16(aA[0][0], S0, ac0, 0,0,0); \
    ac1 = __builtin_amdgcn_mfma_f32_16x16x32_bf16(aA[1][0], S0, ac1, 0,0,0); \
    ac0 = __builtin_amdgcn_mfma_f32_16x16x32_bf16(aA[0][1], S1, ac0, 0,0,0); \
    ac1 = __builtin_amdgcn_mfma_f32_16x16x32_bf16(aA[1][1], S1, ac1, 0,0,0); \
    ac0 = __builtin_amdgcn_mfma_f32_16x16x32_bf16(aA[0][2], S2, ac0, 0,0,0); \
    ac1 = __builtin_amdgcn_mfma_f32_16x16x32_bf16(aA[1][2], S2, ac1, 0,0,0); \
    ac0 = __builtin_amdgcn_mfma_f32_16x16x32_bf16(aA[0][3], S3, ac0, 0,0,0); \
    ac1 = __builtin_amdgcn_mfma_f32_16x16x32_bf16(aA[1][3], S3, ac1, 0,0,0); }

// 2-level fold (xor 1,2) + 4-carrier atomicMax: carriers (l15&3)==0 cover the
// four disjoint 4-lane groups -> rmaxI receives max over ALL 16 lanes.
#define RMAX_SHARE() { \
    _Pragma("unroll") \
    for (int a2 = 0; a2 < 2; ++a2) { \
        _Pragma("unroll") \
        for (int g2 = 0; g2 < 4; ++g2) { \
            float vv = rmaxL[a2 * 4 + g2]; \
            vv = fmaxf(vv, __shfl_xor(vv, 1, 64)); \
            vv = fmaxf(vv, __shfl_xor(vv, 2, 64)); \
            rmaxL[a2 * 4 + g2] = vv; \
            if ((l15 & 3) == 0) \
                atomicMax(&rmaxI[a2 * 16 + quad * 4 + g2], fkey(vv)); \
        } } }

#define THR_REFRESH() { \
    _Pragma("unroll") \
    for (int a2 = 0; a2 < 2; ++a2) { \
        _Pragma("unroll") \
        for (int g2 = 0; g2 < 4; ++g2) \
            thrR[a2 * 4 + g2] = funkey(__hip_atomic_load( \
                    &rmaxI[a2 * 16 + quad * 4 + g2], \
                    __ATOMIC_RELAXED, __HIP_MEMORY_SCOPE_WORKGROUP)) - CUTU; \
    } }

// per-lane collect: order nondeterministic, final SET deterministic
#define COLLECT(TT) { \
    _Pragma("unroll") \
    for (int a2 = 0; a2 < 2; ++a2) { \
        _Pragma("unroll") \
        for (int g2 = 0; g2 < 4; ++g2) { \
            const int j2 = a2 * 4 + g2; \
            const float sc = (a2 == 0) ? ac0[g2] : ac1[g2]; \
            rmaxL[j2] = fmaxf(rmaxL[j2], sc); \
            if (sc > thrR[j2]) { \
                const int row = a2 * 16 + quad * 4 + g2; \
                const int idx = atomicAdd(&cnt[row], 1); \
                if (idx < CAPS) { \
                    candK[row * CAPS + idx] = \
                        (unsigned short)((TT) * 64 + 16 * wave + l15); \
                    candS[row * CAPS + idx] = sc; \
                } } } } }

    f32x4 ac0, ac1;

    // ---- pre-peek tiles 0,1: seed shared row maxima (no collection) ----
    {
        bf16x8 P0, P1, P2, P3;
        #pragma unroll 1
        for (int tp = 0; tp < 2; ++tp) {
            LOADT(P0, P1, P2, P3, tp);
            MFMA8(P0, P1, P2, P3);
            #pragma unroll
            for (int a = 0; a < 2; ++a)
                #pragma unroll
                for (int g = 0; g < 4; ++g)
                    rmaxL[a * 4 + g] = fmaxf(rmaxL[a * 4 + g],
                                             (a == 0) ? ac0[g] : ac1[g]);
        }
        RMAX_SHARE();
    }
    __syncthreads();
    THR_REFRESH();

    // ============== main pass: 2-tile ping-pong register pipeline ==============
    bf16x8 A0, A1, A2, A3, B0, B1, B2, B3;
    LOADT(A0, A1, A2, A3, 0);
    LOADT(B0, B1, B2, B3, 1);

    #pragma unroll 1
    for (int i = 0; i < KL / 128; ++i) {        // 16 iterations, 2 tiles each
        const int tA = 2 * i, tB = 2 * i + 1;
        MFMA8(A0, A1, A2, A3);
        { const int tn = (tA + 2 < KL / 64) ? tA + 2 : KL / 64 - 1;
          LOADT(A0, A1, A2, A3, tn); }
        COLLECT(tA);
        MFMA8(B0, B1, B2, B3);
        { const int tn = (tB + 2 < KL / 64) ? tB + 2 : KL / 64 - 1;
          LOADT(B0, B1, B2, B3, tn); }
        COLLECT(tB);
        if (i & 1) { RMAX_SHARE(); THR_REFRESH(); }
    }
    // tile 31 hit the reduce -> rmaxI now holds the exact row maxima
    __syncthreads();

    // ---- exact final max, prune superset, sort ascending, write to workspace ----
    if (tid < TQ) {
        const float rm = funkey(rmaxI[tid]);
        const float thr = rm - CUTU;            // same fp32 op as two-pass kernel
        const int n0 = min(cnt[tid], CAPS);
        unsigned short* ck = &candK[tid * CAPS];
        float* cs = &candS[tid * CAPS];
        int m = 0;
        for (int i = 0; i < n0; ++i)
            if (cs[i] > thr) ck[m++] = ck[i];   // exact final candidate set
        if (m > CAPF) m = CAPF;
        for (int i = 1; i < m; ++i) {
            const unsigned short key = ck[i];
            int j = i - 1;
            while (j >= 0 && ck[j] > key) { ck[j + 1] = ck[j]; --j; }
            ck[j + 1] = key;
        }
        const int grow = bh * KL + q0 + tid;
        gcnt[grow] = m;
        unsigned short* gc = gcand + (size_t)grow * CAPF;
        for (int i = 0; i < m; ++i) gc[i] = ck[i];
    }
}

// ======================= kernel 2: exact finisher (256 thr) =======================
__global__ void __launch_bounds__(256)
attn_finish(const float* __restrict__ qp, const float* __restrict__ kp,
            const float* __restrict__ vp, const float* __restrict__ queryp,
            const unsigned char* __restrict__ maskp,
            const int* __restrict__ gcnt, const unsigned short* __restrict__ gcand,
            int* __restrict__ outp)
{
#pragma clang fp contract(off)
    __shared__ float          Qs[TQ * QP];      // fp32 Q rows (reused as softmax pad)
    __shared__ int            cntA[TQ];
    __shared__ unsigned short candK[TQ * CAPF];
    __shared__ float          candS[TQ * CAPF];
    __shared__ float          candA[TQ * CAPF];
    __shared__ float          rowM[TQ];
    __shared__ float          rowSig[TQ];

    const int tid = threadIdx.x;

    const int lin = blockIdx.y * (KL / TQ) + blockIdx.x;   // 0..2047
    const int nl  = (lin & 7) * 256 + (lin >> 3);          // same swizzle as screen
    const int bh  = nl >> 6;
    const int q0  = (nl & 63) * TQ;

    const size_t base = (size_t)bh * (KL * KD);
    const int rowbase = bh * KL + q0;

    // ---- stage Q fp32 into LDS + pull candidates from workspace ----
    #pragma unroll
    for (int i = 0; i < 4; ++i) {
        const int idx = tid + i * 256, r = idx >> 5, c4 = (idx & 31) << 2;
        *(float4*)&Qs[r * QP + c4] =
            *(const float4*)(qp + base + (size_t)(q0 + r) * KD + c4);
    }
    {
        const unsigned short* gc = gcand + (size_t)rowbase * CAPF;
        #pragma unroll
        for (int i = 0; i < (TQ * CAPF + 255) / 256; ++i) {
            const int idx = tid + i * 256;
            if (idx < TQ * CAPF) candK[idx] = gc[idx];
        }
        if (tid < TQ) cntA[tid] = gcnt[rowbase + tid];
    }
    __syncthreads();

    // ================= exact fp32 dots for candidates (BLAS chain) =================
    {
        const int r = tid >> 3, j = tid & 7;
        const int n = cntA[r];
        const float* qrow = &Qs[r * QP];
        for (int i = j; i < n; i += 8) {
            const int kk = candK[r * CAPF + i];
            const float* krow = kp + base + (size_t)kk * KD;
            float s = 0.f;
            #pragma unroll 8
            for (int d = 0; d < KD; d += 4) {
                const float4 kv = *(const float4*)(krow + d);
                const float4 qv = *(const float4*)(qrow + d);
                s = fmaf(qv.x, kv.x, s);
                s = fmaf(qv.y, kv.y, s);
                s = fmaf(qv.z, kv.z, s);
                s = fmaf(qv.w, kv.w, s);
            }
            candS[r * CAPF + i] = s * SCALEF;
        }
    }
    __syncthreads();

    // ---- c1: per-row max (serial, n~4.5) ----
    if (tid < TQ) {
        const int n = cntA[tid];
        float m = -3.4e38f;
        for (int i = 0; i < n; ++i) m = fmaxf(m, candS[tid * CAPF + i]);
        rowM[tid] = m;
    }
    __syncthreads();

    // ---- c2: exp parallel 8 threads/row (same fp64 exp expression) ----
    {
        const int r = tid >> 3, j = tid & 7;
        const int n = cntA[r];
        const float m = rowM[r];
        for (int i = j; i < n; i += 8) {
            const float dm = candS[r * CAPF + i] - m;     // fp32 sub
            candA[r * CAPF + i] = (float)exp((double)dm); // ~correctly-rounded fp32 exp
        }
    }
    __syncthreads();

    // ---- c3: numpy pairwise denominator (AVX512 model), cb==2 fast path ----
    if (tid < TQ) {
        const int r = tid, n = cntA[r];
        float* E = &Qs[r * 129];    // reuse Q storage as 128-slot scatter pad
        float leaves[16];
        int p = 0;
        #pragma unroll 1
        for (int b = 0; b < 16; ++b) {
            const int pstart = p;
            while (p < n && (candK[r * CAPF + p] >> 7) == b) ++p;
            const int cb = p - pstart;
            float leaf = 0.0f;
            if (cb == 1) {
                leaf = candA[r * CAPF + pstart];
            } else if (cb == 2) {
                leaf = candA[r * CAPF + pstart] + candA[r * CAPF + pstart + 1];
            } else if (cb >= 3) {
                for (int jj = 0; jj < 128; ++jj) E[jj] = 0.0f;
                for (int jj = pstart; jj < p; ++jj)
                    E[candK[r * CAPF + jj] & 127] = candA[r * CAPF + jj];
                float R[16];
                for (int l = 0; l < 16; ++l)
                    R[l] = ((E[l] + E[16 + l]) + (E[32 + l] + E[48 + l]))
                         + ((E[64 + l] + E[80 + l]) + (E[96 + l] + E[112 + l]));
                for (int l = 0; l < 8; ++l) R[l] = R[l] + R[l + 8];
                for (int l = 0; l < 4; ++l) R[l] = R[l] + R[l + 4];
                R[0] = R[0] + R[2]; R[1] = R[1] + R[3];
                leaf = R[0] + R[1];
            }
            leaves[b] = leaf;
        }
        float t2[8], t3[4];
        for (int jj = 0; jj < 8; ++jj) t2[jj] = leaves[2 * jj] + leaves[2 * jj + 1];
        for (int jj = 0; jj < 4; ++jj) t3[jj] = t2[2 * jj] + t2[2 * jj + 1];
        rowSig[r] = (t3[0] + t3[1]) + (t3[2] + t3[3]);
    }
    __syncthreads();

    // ---- c4: division parallel 8 threads/row (IEEE fp32 div, same op) ----
    {
        const int r = tid >> 3, j = tid & 7;
        const int n = cntA[r];
        const float sig = rowSig[r];
        for (int i = j; i < n; i += 8)
            candA[r * CAPF + i] = candA[r * CAPF + i] / sig;
    }
    __syncthreads();

    // ====== numerator: FMA chain per 384-chunk, chunks added in order ======
    // Batched V loads: 8 independent predicated loads per batch, consumed in
    // candidate order. Skipped empty-chunk adds are exact +0 identities
    // (part is never -0), so the fp32 chain is bit-identical to the reference.
    for (int rr = 0; rr < TQ; rr += 2) {
        const int r = rr + (tid >> 7);
        const int d = tid & 127;
        const int n = cntA[r];
        float o = 0.0f, part = 0.0f;
        int cprev = 0;
        #pragma unroll 1
        for (int i0 = 0; i0 < n; i0 += 8) {
            float pa[8], pv[8]; int pc[8];
            #pragma unroll
            for (int u = 0; u < 8; ++u) {
                const int ix = i0 + u;
                const bool act = ix < n;
                const int kk = act ? (int)candK[r * CAPF + ix] : 0;
                pa[u] = act ? candA[r * CAPF + ix] : 0.0f;
                pc[u] = act ? ((kk * 683) >> 18) : 0;      // kk/384, exact for kk<2048
                pv[u] = act ? vp[base + (size_t)kk * KD + d] : 0.0f;
            }
            #pragma unroll
            for (int u = 0; u < 8; ++u) {
                if (i0 + u < n) {
                    if (pc[u] != cprev) { o = o + part; part = 0.0f; cprev = pc[u]; }
                    part = fmaf(pa[u], pv[u], part);
                }
            }
        }
        o = o + part;
        int res = (int)o;
        const int grow = q0 + r;
        if (maskp[(size_t)bh * KL + grow])
            res = (int)queryp[base + (size_t)grow * KD + d];
        outp[base + (size_t)grow * KD + d] = res;
    }
}

extern "C" void kernel_launch(void* const* d_in, const int* in_sizes, int n_in,
                              void* d_out, int out_size, void* d_ws, size_t ws_size,
                              hipStream_t stream) {
    const float* q     = (const float*)d_in[0];
    const float* k     = (const float*)d_in[1];
    const float* v     = (const float*)d_in[2];
    const float* query = (const float*)d_in[3];
    const unsigned char* mask = (const unsigned char*)d_in[4];
    // d_in[5] = dropout_p (static 0) -> identity, ignored.
    int* out = (int*)d_out;

    // workspace layout: kh (16.8MB, fragment order) | gcnt (0.26MB) | gcand (5.24MB)
    unsigned short* kh    = (unsigned short*)d_ws;
    int*            gcnt  = (int*)((char*)d_ws + (size_t)KH_ELEMS * 2);
    unsigned short* gcand = (unsigned short*)((char*)d_ws + (size_t)KH_ELEMS * 2
                                              + (size_t)NROWS * 4);

    // pre-pass: K fp32 -> bf16 fragment-order (1048576 16B chunks)
    cvt_k_frag<<<dim3(4096), dim3(256), 0, stream>>>(k, kh);

    dim3 grid(KL / TQ, 32, 1);
    attn_screen<<<grid, dim3(256), 0, stream>>>(q, kh, gcnt, gcand);
    attn_finish<<<grid, dim3(256), 0, stream>>>(q, k, v, query, mask, gcnt, gcand, out);
}